// Round 4
// baseline (16110.056 us; speedup 1.0000x reference)
//
#include <hip/hip_runtime.h>
#include <math.h>

// LITERAL reference implementation. One block = one batch element.
// No algebraic folding anywhere: every intermediate (y, k, q, v, kq, sm, att)
// is materialized exactly as in the reference. Correctness oracle round.

__global__ __launch_bounds__(256, 1)
void literal_kernel(const float* __restrict__ in0,
                    const float* __restrict__ emb,
                    const float* __restrict__ wk11, const float* __restrict__ wq11,
                    const float* __restrict__ wv11,
                    const float* __restrict__ wk12, const float* __restrict__ wq12,
                    const float* __restrict__ wv12,
                    const float* __restrict__ l1,
                    const float* __restrict__ wk21, const float* __restrict__ wq21,
                    const float* __restrict__ wv21,
                    const float* __restrict__ wk22, const float* __restrict__ wq22,
                    const float* __restrict__ wv22,
                    const float* __restrict__ l2,
                    const float* __restrict__ L3, const float* __restrict__ L4,
                    float* __restrict__ out)
{
    __shared__ float xsh[66];
    __shared__ float ysh[128 * 66];   // y[j][s] at j*66+s ; stage2: Ysw[h][s]
    __shared__ float ksh[128 * 66];   // k[i][s] at i*66+s ; then att[s*128+i]
    __shared__ float qsh[128 * 66];   // q[i][s] / q2[i][s]
    __shared__ float vsh[128 * 66];   // v[i][s] / v2[i][s]
    __shared__ float kqsh[65 * 66];   // kq[s][t] at s*66+t ; sm in place
    __shared__ float k2col[128];
    __shared__ float attr[128];
    __shared__ float lshf[66];
    __shared__ float smr[66];
    __shared__ float y4sh[128];

    const int tid  = threadIdx.x;
    const int w    = tid >> 6;      // wave id 0..3
    const int lane = tid & 63;
    const long b   = blockIdx.x;

    if (tid < 64) xsh[tid] = in0[b * 64 + tid];
    if (tid == 64) xsh[64] = 1.0f;
    __syncthreads();

    // y[j][s] = emb[j][s] * x[s]
    for (int idx = tid; idx < 8320; idx += 256) {
        int j = idx / 65, s = idx - j * 65;
        ysh[j * 66 + s] = emb[j * 65 + s] * xsh[s];
    }
    __syncthreads();

    // pre1 accumulators: thread owns h = 4*(tid&31)..+3, s = (tid>>5) + 8*si
    const int h4 = (tid & 31) * 4;
    const int sb = tid >> 5;
    float4 acc1[9];
    #pragma unroll
    for (int si = 0; si < 9; ++si) acc1[si] = make_float4(0.f, 0.f, 0.f, 0.f);

    for (int a = 0; a < 2; ++a) {
        const float* wk = a ? wk12 : wk11;
        const float* wq = a ? wq12 : wq11;
        const float* wv = a ? wv12 : wv11;

        // k,q,v = w @ y  (wave handles rows i = w+4r; lanes are s=0..63)
        for (int i = w; i < 128; i += 4) {
            float aK = 0.f, aQ = 0.f, aV = 0.f;
            for (int j = 0; j < 128; ++j) {
                float yv = ysh[j * 66 + lane];
                aK = fmaf(wk[i * 128 + j], yv, aK);
                aQ = fmaf(wq[i * 128 + j], yv, aQ);
                aV = fmaf(wv[i * 128 + j], yv, aV);
            }
            ksh[i * 66 + lane] = aK;
            qsh[i * 66 + lane] = aQ;
            vsh[i * 66 + lane] = aV;
        }
        if (tid < 128) {  // cleanup column s=64
            float aK = 0.f, aQ = 0.f, aV = 0.f;
            for (int j = 0; j < 128; ++j) {
                float yv = ysh[j * 66 + 64];
                aK = fmaf(wk[tid * 128 + j], yv, aK);
                aQ = fmaf(wq[tid * 128 + j], yv, aQ);
                aV = fmaf(wv[tid * 128 + j], yv, aV);
            }
            ksh[tid * 66 + 64] = aK;
            qsh[tid * 66 + 64] = aQ;
            vsh[tid * 66 + 64] = aV;
        }
        __syncthreads();

        // kq[s][t] = sum_i k[i][s] * q[i][t]
        for (int idx = tid; idx < 4225; idx += 256) {
            int s = idx / 65, t = idx - s * 65;
            float acc = 0.f;
            for (int i = 0; i < 128; ++i)
                acc = fmaf(ksh[i * 66 + s], qsh[i * 66 + t], acc);
            kqsh[s * 66 + t] = acc;
        }
        __syncthreads();

        // softmax over t, in place
        for (int s = w; s < 65; s += 4) {
            float lg   = kqsh[s * 66 + lane];
            float l64v = (lane == 0) ? kqsh[s * 66 + 64] : -3.0e38f;
            float mm = fmaxf(lg, l64v);
            #pragma unroll
            for (int off = 32; off >= 1; off >>= 1) mm = fmaxf(mm, __shfl_xor(mm, off));
            float e   = expf(lg - mm);
            float e64 = (lane == 0) ? expf(l64v - mm) : 0.f;
            float zs = e + e64;
            #pragma unroll
            for (int off = 32; off >= 1; off >>= 1) zs += __shfl_xor(zs, off);
            float inv = 1.0f / zs;
            kqsh[s * 66 + lane] = e * inv;
            if (lane == 0) kqsh[s * 66 + 64] = e64 * inv;
        }
        __syncthreads();

        // att[s][i] = sum_t sm[s][t] * v[i][t]  -> overwrite ksh (k is dead)
        for (int idx = tid; idx < 8320; idx += 256) {
            int s = idx >> 7, i = idx & 127;
            float acc = 0.f;
            for (int t = 0; t < 65; ++t)
                acc = fmaf(kqsh[s * 66 + t], vsh[i * 66 + t], acc);
            ksh[s * 128 + i] = acc;
        }
        __syncthreads();

        // pre1[s][h] += sum_i att[s][i] * l1[(a*128+i)*128 + h]
        const float* l1a = l1 + a * 128 * 128;
        #pragma unroll
        for (int si = 0; si < 9; ++si) {
            int s = sb + si * 8;
            if (s < 65) {
                float4 acc = acc1[si];
                for (int i = 0; i < 128; ++i) {
                    float av = ksh[s * 128 + i];
                    float4 lv = *(const float4*)&l1a[i * 128 + h4];
                    acc.x = fmaf(av, lv.x, acc.x);
                    acc.y = fmaf(av, lv.y, acc.y);
                    acc.z = fmaf(av, lv.z, acc.z);
                    acc.w = fmaf(av, lv.w, acc.w);
                }
                acc1[si] = acc;
            }
        }
        __syncthreads();   // protect ksh/qsh/vsh/kqsh for next a
    }

    // Y = tanh(pre1); store transposed Ysw[h][s] into ysh (y dead)
    #pragma unroll
    for (int si = 0; si < 9; ++si) {
        int s = sb + si * 8;
        if (s < 65) {
            float4 acc = acc1[si];
            ysh[(h4 + 0) * 66 + s] = tanhf(acc.x);
            ysh[(h4 + 1) * 66 + s] = tanhf(acc.y);
            ysh[(h4 + 2) * 66 + s] = tanhf(acc.z);
            ysh[(h4 + 3) * 66 + s] = tanhf(acc.w);
        }
    }
    __syncthreads();

    // ---- stage 2 (literal; only row s=64 of kq2 is ever used downstream) ----
    float pre2 = 0.f;   // valid for tid < 128 (h = tid)
    for (int a2 = 0; a2 < 2; ++a2) {
        const float* wk2 = a2 ? wk22 : wk21;
        const float* wq2 = a2 ? wq22 : wq21;
        const float* wv2 = a2 ? wv22 : wv21;

        for (int i = w; i < 128; i += 4) {
            float aQ = 0.f, aV = 0.f;
            for (int h = 0; h < 128; ++h) {
                float yv = ysh[h * 66 + lane];
                aQ = fmaf(wq2[i * 128 + h], yv, aQ);
                aV = fmaf(wv2[i * 128 + h], yv, aV);
            }
            qsh[i * 66 + lane] = aQ;
            vsh[i * 66 + lane] = aV;
        }
        if (tid < 128) {
            float aQ = 0.f, aV = 0.f, aK = 0.f;
            for (int h = 0; h < 128; ++h) {
                float yv = ysh[h * 66 + 64];
                aQ = fmaf(wq2[tid * 128 + h], yv, aQ);
                aV = fmaf(wv2[tid * 128 + h], yv, aV);
                aK = fmaf(wk2[tid * 128 + h], yv, aK);
            }
            qsh[tid * 66 + 64] = aQ;
            vsh[tid * 66 + 64] = aV;
            k2col[tid] = aK;          // k2[:, 64]
        }
        __syncthreads();

        // kq2[64][t] = sum_i k2[i][64] * q2[i][t]
        if (tid < 65) {
            float acc = 0.f;
            for (int i = 0; i < 128; ++i)
                acc = fmaf(k2col[i], qsh[i * 66 + tid], acc);
            lshf[tid] = acc;
        }
        __syncthreads();
        if (w == 0) {
            float lg   = lshf[lane];
            float l64v = (lane == 0) ? lshf[64] : -3.0e38f;
            float mm = fmaxf(lg, l64v);
            #pragma unroll
            for (int off = 32; off >= 1; off >>= 1) mm = fmaxf(mm, __shfl_xor(mm, off));
            float e   = expf(lg - mm);
            float e64 = (lane == 0) ? expf(l64v - mm) : 0.f;
            float zs = e + e64;
            #pragma unroll
            for (int off = 32; off >= 1; off >>= 1) zs += __shfl_xor(zs, off);
            float inv = 1.0f / zs;
            smr[lane] = e * inv;
            if (lane == 0) smr[64] = e64 * inv;
        }
        __syncthreads();

        // att2[64][i] = sum_t sm[64][t] * v2[i][t]
        if (tid < 128) {
            float acc = 0.f;
            for (int t = 0; t < 65; ++t)
                acc = fmaf(smr[t], vsh[tid * 66 + t], acc);
            attr[tid] = acc;
        }
        __syncthreads();

        // pre2[h] += sum_i att2[64][i] * l2[(a2*128+i)*128 + h]
        if (tid < 128) {
            const float* l2a = l2 + a2 * 128 * 128;
            float acc = pre2;
            for (int i = 0; i < 128; ++i)
                acc = fmaf(attr[i], l2a[i * 128 + tid], acc);
            pre2 = acc;
        }
        __syncthreads();
    }

    if (tid < 128) y4sh[tid] = tanhf(pre2);
    __syncthreads();

    if (tid < 64) {
        float t3 = 0.f;
        for (int h = 0; h < 128; ++h)
            t3 = fmaf(y4sh[h], L3[h * 64 + tid], t3);
        float y5 = tanhf(t3);
        float sc = y5 * L4[tid];
        #pragma unroll
        for (int off = 32; off >= 1; off >>= 1) sc += __shfl_xor(sc, off);
        if (tid == 0) out[b] = sc;
    }
}

extern "C" void kernel_launch(void* const* d_in, const int* in_sizes, int n_in,
                              void* d_out, int out_size, void* d_ws, size_t ws_size,
                              hipStream_t stream) {
    const float* in0  = (const float*)d_in[0];
    const float* emb  = (const float*)d_in[1];
    const float* wk11 = (const float*)d_in[2];
    const float* wq11 = (const float*)d_in[3];
    const float* wv11 = (const float*)d_in[4];
    const float* wk12 = (const float*)d_in[5];
    const float* wq12 = (const float*)d_in[6];
    const float* wv12 = (const float*)d_in[7];
    const float* l1   = (const float*)d_in[8];
    const float* wk21 = (const float*)d_in[9];
    const float* wq21 = (const float*)d_in[10];
    const float* wv21 = (const float*)d_in[11];
    const float* wk22 = (const float*)d_in[12];
    const float* wq22 = (const float*)d_in[13];
    const float* wv22 = (const float*)d_in[14];
    const float* l2   = (const float*)d_in[15];
    const float* l3   = (const float*)d_in[16];
    const float* l4   = (const float*)d_in[17];
    float* out = (float*)d_out;

    int B = in_sizes[0] / 64;   // 8192

    literal_kernel<<<B, 256, 0, stream>>>(in0, emb,
                                          wk11, wq11, wv11, wk12, wq12, wv12, l1,
                                          wk21, wq21, wv21, wk22, wq22, wv22, l2,
                                          l3, l4, out);
}